// Round 1
// baseline (3426.250 us; speedup 1.0000x reference)
//
#include <hip/hip_runtime.h>
#include <hip/hip_bf16.h>

typedef __bf16 bf16x8 __attribute__((ext_vector_type(8)));
typedef float f32x4 __attribute__((ext_vector_type(4)));

#define NH 12
#define HD 64
#define SEQ 145
#define SP 160
#define DMODEL 768
#define NTOT 2304
#define BDIM 1024

// f32 -> bf16 RNE
__device__ __forceinline__ ushort f2bf(float f) {
  union { float f; uint u; } a; a.f = f;
  uint u = a.u;
  return (ushort)((u + 0x7FFFu + ((u >> 16) & 1u)) >> 16);
}

__device__ __forceinline__ int relidx(int qi, int ki) {
  if (ki == 0) return (qi == 0) ? 531 : 530;
  if (qi == 0) return 529;
  int q = qi - 1, k = ki - 1;
  int qh = q / 12, qw = q - qh * 12;
  int kh = k / 12, kw = k - kh * 12;
  return (qh - kh + 11) * 23 + (qw - kw + 11);
}

// ---------------- prep: Wt[n][k] = W_sel[k][n%768] as bf16 ----------------
__global__ void prep_w(const float* __restrict__ Wq, const float* __restrict__ Wk,
                       const float* __restrict__ Wv, ushort* __restrict__ Wt) {
  int i = blockIdx.x * 256 + threadIdx.x;
  if (i >= NTOT * DMODEL) return;
  int n = i / DMODEL, k = i - n * DMODEL;
  const float* W = (n < DMODEL) ? Wq : (n < 2 * DMODEL ? Wk : Wv);
  int c = n % DMODEL;
  Wt[i] = f2bf(W[k * DMODEL + c]);
}

// ---------------- zero pad region of transposed V buffer ----------------
__global__ void zero_vpad(ushort* __restrict__ vbuf) {
  int i = blockIdx.x * 256 + threadIdx.x;
  const int total = BDIM * NH * HD * (SP - SEQ);
  if (i >= total) return;
  int s = SEQ + i % (SP - SEQ);
  int row = i / (SP - SEQ);
  vbuf[(size_t)row * SP + s] = 0;
}

// ---------------- fused QKV GEMM: [148480,768] x [768,2304] ----------------
#define BM 128
#define BN 128
#define BK 64
#define TN_TILES 18

__global__ __launch_bounds__(256)
void qkv_gemm(const float* __restrict__ x, const ushort* __restrict__ Wt,
              const float* __restrict__ bq, const float* __restrict__ bv,
              ushort* __restrict__ qbuf, ushort* __restrict__ kbuf,
              ushort* __restrict__ vbuf) {
  __shared__ __align__(16) ushort Alds[BM][BK + 8];
  __shared__ __align__(16) ushort Blds[BN][BK + 8];

  int id = blockIdx.x;
  // XCD-aware: each XCD walks n fastest over its own set of m-panels
  int xcd = id & 7;
  int j = id >> 3;
  int mt = xcd + 8 * (j / TN_TILES);
  int nt = j % TN_TILES;
  int m0 = mt * BM, n0 = nt * BN;

  int tid = threadIdx.x;
  int lane = tid & 63, wid = tid >> 6;
  int wr = wid >> 1, wc = wid & 1;

  f32x4 acc[4][4];
  #pragma unroll
  for (int a = 0; a < 4; a++)
    #pragma unroll
    for (int c = 0; c < 4; c++)
      #pragma unroll
      for (int e = 0; e < 4; e++) acc[a][c][e] = 0.f;

  int arow = tid >> 1;
  int akc = (tid & 1) * 32;

  for (int k0 = 0; k0 < DMODEL; k0 += BK) {
    __syncthreads();
    // stage A (f32 -> bf16)
    const float* xp = x + (size_t)(m0 + arow) * DMODEL + k0 + akc;
    #pragma unroll
    for (int i = 0; i < 8; i++) {
      float4 v = *reinterpret_cast<const float4*>(xp + i * 4);
      ushort4 p;
      p.x = f2bf(v.x); p.y = f2bf(v.y); p.z = f2bf(v.z); p.w = f2bf(v.w);
      *reinterpret_cast<ushort4*>(&Alds[arow][akc + i * 4]) = p;
    }
    // stage B (bf16 direct)
    const ushort* wp = Wt + (size_t)(n0 + arow) * DMODEL + k0 + akc;
    #pragma unroll
    for (int i = 0; i < 4; i++) {
      uint4 v = *reinterpret_cast<const uint4*>(wp + i * 8);
      *reinterpret_cast<uint4*>(&Blds[arow][akc + i * 8]) = v;
    }
    __syncthreads();

    #pragma unroll
    for (int kk = 0; kk < 2; kk++) {
      int kb = kk * 32 + (lane >> 4) * 8;
      bf16x8 af[4], bfv[4];
      #pragma unroll
      for (int m = 0; m < 4; m++)
        af[m] = *reinterpret_cast<const bf16x8*>(&Alds[wr * 64 + m * 16 + (lane & 15)][kb]);
      #pragma unroll
      for (int n = 0; n < 4; n++)
        bfv[n] = *reinterpret_cast<const bf16x8*>(&Blds[wc * 64 + n * 16 + (lane & 15)][kb]);
      #pragma unroll
      for (int m = 0; m < 4; m++)
        #pragma unroll
        for (int n = 0; n < 4; n++)
          acc[m][n] = __builtin_amdgcn_mfma_f32_16x16x32_bf16(af[m], bfv[n], acc[m][n], 0, 0, 0);
    }
  }

  // epilogue: which sub-matrix (q/k/v) is uniform per block (768 % 128 == 0)
  int which = n0 / DMODEL;
  #pragma unroll
  for (int nf = 0; nf < 4; nf++) {
    int col = n0 + wc * 64 + nf * 16 + (lane & 15);
    int hcol = col - which * DMODEL;
    int h = hcol >> 6, dh = hcol & 63;
    float bias = (which == 0) ? bq[hcol] : (which == 2 ? bv[hcol] : 0.f);
    #pragma unroll
    for (int mf = 0; mf < 4; mf++) {
      int rowb = m0 + wr * 64 + mf * 16 + ((lane >> 4) << 2);
      #pragma unroll
      for (int r = 0; r < 4; r++) {
        int row = rowb + r;
        int b = row / SEQ;
        int s = row - b * SEQ;
        float v = acc[mf][nf][r] + bias;
        size_t bh = (size_t)b * NH + h;
        if (which == 0) {
          v *= 0.125f;  // fold 1/sqrt(64)
          qbuf[(bh * SEQ + s) * HD + dh] = f2bf(v);
        } else if (which == 1) {
          kbuf[(bh * SEQ + s) * HD + dh] = f2bf(v);
        } else {
          vbuf[(bh * HD + dh) * SP + s] = f2bf(v);  // transposed + padded
        }
      }
    }
  }
}

// ---------------- fused windowed attention ----------------
__global__ __launch_bounds__(320)
void attn_kernel(const ushort* __restrict__ qbuf, const ushort* __restrict__ kbuf,
                 const ushort* __restrict__ vbuf, const float* __restrict__ mask,
                 const float* __restrict__ tbl, float* __restrict__ out) {
  __shared__ __align__(16) ushort klds[SP][HD + 8];       // [160][72]
  __shared__ __align__(16) ushort vlds[HD][SP + 8];       // [64][168]
  __shared__ __align__(16) ushort plds[5][16][SP + 8];    // per-wave P

  int bh = blockIdx.x;
  int b = bh / NH, h = bh - b * NH;
  int tid = threadIdx.x;
  int lane = tid & 63, wid = tid >> 6;

  // stage K [160][72], zero pad rows
  const ushort* kp = kbuf + (size_t)bh * SEQ * HD;
  for (int c = tid; c < (SP * HD) / 8; c += 320) {
    int s = c >> 3, d0 = (c & 7) * 8;
    uint4 v;
    if (s < SEQ) v = *reinterpret_cast<const uint4*>(kp + s * HD + d0);
    else v = make_uint4(0, 0, 0, 0);
    *reinterpret_cast<uint4*>(&klds[s][d0]) = v;
  }
  // stage V^T [64][168] from padded vbuf [64][160]
  const ushort* vp = vbuf + (size_t)bh * HD * SP;
  for (int c = tid; c < (HD * SP) / 8; c += 320) {
    int d = c / (SP / 8), s0 = (c % (SP / 8)) * 8;
    uint4 v = *reinterpret_cast<const uint4*>(vp + d * SP + s0);
    *reinterpret_cast<uint4*>(&vlds[d][s0]) = v;
  }
  __syncthreads();

  const ushort* qp = qbuf + (size_t)bh * SEQ * HD;
  const float* mp = mask + (size_t)b * SEQ * SEQ;

  for (int half = 0; half < 2; half++) {
    int r0 = (wid * 2 + half) * 16;
    // Q fragments straight from global
    bf16x8 qf[2];
    int qrow = r0 + (lane & 15);
    if (qrow < SEQ) {
      qf[0] = *reinterpret_cast<const bf16x8*>(qp + qrow * HD + ((lane >> 4) * 8));
      qf[1] = *reinterpret_cast<const bf16x8*>(qp + qrow * HD + 32 + ((lane >> 4) * 8));
    } else {
      uint4 z = make_uint4(0, 0, 0, 0);
      qf[0] = *reinterpret_cast<bf16x8*>(&z);
      qf[1] = *reinterpret_cast<bf16x8*>(&z);
    }

    // scores: 10 column tiles
    f32x4 sc[10];
    #pragma unroll
    for (int ct = 0; ct < 10; ct++)
      #pragma unroll
      for (int e = 0; e < 4; e++) sc[ct][e] = 0.f;
    #pragma unroll
    for (int ct = 0; ct < 10; ct++) {
      #pragma unroll
      for (int kk = 0; kk < 2; kk++) {
        bf16x8 bfv = *reinterpret_cast<const bf16x8*>(
            &klds[ct * 16 + (lane & 15)][kk * 32 + (lane >> 4) * 8]);
        sc[ct] = __builtin_amdgcn_mfma_f32_16x16x32_bf16(qf[kk], bfv, sc[ct], 0, 0, 0);
      }
    }

    // mask + rel bias
    int qi[4];
    #pragma unroll
    for (int r = 0; r < 4; r++) qi[r] = r0 + ((lane >> 4) << 2) + r;
    float mx[4] = {-3e38f, -3e38f, -3e38f, -3e38f};
    #pragma unroll
    for (int ct = 0; ct < 10; ct++) {
      int ki = ct * 16 + (lane & 15);
      #pragma unroll
      for (int r = 0; r < 4; r++) {
        float sv;
        if (ki < SEQ && qi[r] < SEQ) {
          sv = sc[ct][r] + mp[qi[r] * SEQ + ki] + tbl[relidx(qi[r], ki) * NH + h];
        } else {
          sv = -3e38f;
        }
        sc[ct][r] = sv;
        mx[r] = fmaxf(mx[r], sv);
      }
    }
    // row max across the 16-lane group
    #pragma unroll
    for (int d = 1; d < 16; d <<= 1)
      #pragma unroll
      for (int r = 0; r < 4; r++) mx[r] = fmaxf(mx[r], __shfl_xor(mx[r], d, 64));
    // exp + sum
    float sum[4] = {0.f, 0.f, 0.f, 0.f};
    #pragma unroll
    for (int ct = 0; ct < 10; ct++)
      #pragma unroll
      for (int r = 0; r < 4; r++) {
        float p = __expf(sc[ct][r] - mx[r]);
        sc[ct][r] = p;
        sum[r] += p;
      }
    #pragma unroll
    for (int d = 1; d < 16; d <<= 1)
      #pragma unroll
      for (int r = 0; r < 4; r++) sum[r] += __shfl_xor(sum[r], d, 64);
    float inv[4];
    #pragma unroll
    for (int r = 0; r < 4; r++) inv[r] = 1.f / sum[r];

    // write P (bf16) to per-wave LDS (C-layout -> A-layout transpose)
    #pragma unroll
    for (int ct = 0; ct < 10; ct++) {
      #pragma unroll
      for (int r = 0; r < 4; r++)
        plds[wid][((lane >> 4) << 2) + r][ct * 16 + (lane & 15)] =
            f2bf(sc[ct][r] * inv[r]);
    }

    // PV: ctx[16 x 64]
    #pragma unroll
    for (int ntl = 0; ntl < 4; ntl++) {
      f32x4 pacc;
      #pragma unroll
      for (int e = 0; e < 4; e++) pacc[e] = 0.f;
      #pragma unroll
      for (int ks = 0; ks < 5; ks++) {
        bf16x8 pa = *reinterpret_cast<const bf16x8*>(
            &plds[wid][lane & 15][ks * 32 + (lane >> 4) * 8]);
        bf16x8 vb = *reinterpret_cast<const bf16x8*>(
            &vlds[ntl * 16 + (lane & 15)][ks * 32 + (lane >> 4) * 8]);
        pacc = __builtin_amdgcn_mfma_f32_16x16x32_bf16(pa, vb, pacc, 0, 0, 0);
      }
      #pragma unroll
      for (int r = 0; r < 4; r++) {
        int s = r0 + ((lane >> 4) << 2) + r;
        if (s < SEQ)
          out[((size_t)b * SEQ + s) * DMODEL + h * HD + ntl * 16 + (lane & 15)] = pacc[r];
      }
    }
  }
}

extern "C" void kernel_launch(void* const* d_in, const int* in_sizes, int n_in,
                              void* d_out, int out_size, void* d_ws, size_t ws_size,
                              hipStream_t stream) {
  const float* x    = (const float*)d_in[0];
  const float* mask = (const float*)d_in[1];
  const float* Wq   = (const float*)d_in[2];
  const float* bq   = (const float*)d_in[3];
  const float* Wk   = (const float*)d_in[4];
  const float* Wv   = (const float*)d_in[5];
  const float* bv   = (const float*)d_in[6];
  const float* tbl  = (const float*)d_in[7];
  float* out = (float*)d_out;

  char* ws = (char*)d_ws;
  ushort* Wt = (ushort*)ws;                         // 3,538,944 B
  size_t off = (size_t)NTOT * DMODEL * 2;
  ushort* qbuf = (ushort*)(ws + off); off += (size_t)BDIM * NH * SEQ * HD * 2;
  ushort* kbuf = (ushort*)(ws + off); off += (size_t)BDIM * NH * SEQ * HD * 2;
  ushort* vbuf = (ushort*)(ws + off); off += (size_t)BDIM * NH * HD * SP * 2;
  // total ~712 MB of d_ws

  prep_w<<<(NTOT * DMODEL + 255) / 256, 256, 0, stream>>>(Wq, Wk, Wv, Wt);
  zero_vpad<<<(BDIM * NH * HD * (SP - SEQ) + 255) / 256, 256, 0, stream>>>(vbuf);

  int mtiles = (BDIM * SEQ) / BM;   // 1160
  qkv_gemm<<<mtiles * TN_TILES, 256, 0, stream>>>(x, Wt, bq, bv, qbuf, kbuf, vbuf);

  attn_kernel<<<BDIM * NH, 320, 0, stream>>>(qbuf, kbuf, vbuf, mask, tbl, out);
}

// Round 2
// 2959.353 us; speedup vs baseline: 1.1578x; 1.1578x over previous
//
#include <hip/hip_runtime.h>
#include <hip/hip_bf16.h>

typedef __bf16 bf16x8 __attribute__((ext_vector_type(8)));
typedef float f32x4 __attribute__((ext_vector_type(4)));

#define NH 12
#define HD 64
#define SEQ 145
#define SP 160
#define DMODEL 768
#define NTOT 2304
#define BDIM 1024

// f32 -> bf16 RNE
__device__ __forceinline__ ushort f2bf(float f) {
  union { float f; uint u; } a; a.f = f;
  uint u = a.u;
  return (ushort)((u + 0x7FFFu + ((u >> 16) & 1u)) >> 16);
}

__device__ __forceinline__ int relidx(int qi, int ki) {
  if (ki == 0) return (qi == 0) ? 531 : 530;
  if (qi == 0) return 529;
  int q = qi - 1, k = ki - 1;
  int qh = q / 12, qw = q - qh * 12;
  int kh = k / 12, kw = k - kh * 12;
  return (qh - kh + 11) * 23 + (qw - kw + 11);
}

// async global->LDS, 16B per lane; lds dest = wave-uniform base + lane*16
__device__ __forceinline__ void gload_lds16(const ushort* g, ushort* l) {
  __builtin_amdgcn_global_load_lds(
      (const __attribute__((address_space(1))) void*)g,
      (__attribute__((address_space(3))) void*)l, 16, 0, 0);
}

// ---------------- prep: Wt[n][k] = W_sel[k][n%768] as bf16 ----------------
__global__ void prep_w(const float* __restrict__ Wq, const float* __restrict__ Wk,
                       const float* __restrict__ Wv, ushort* __restrict__ Wt) {
  int i = blockIdx.x * 256 + threadIdx.x;
  if (i >= NTOT * DMODEL) return;
  int n = i / DMODEL, k = i - n * DMODEL;
  const float* W = (n < DMODEL) ? Wq : (n < 2 * DMODEL ? Wk : Wv);
  int c = n % DMODEL;
  Wt[i] = f2bf(W[k * DMODEL + c]);
}

// ---------------- x f32 -> bf16 (into d_out scratch) ----------------
__global__ void x2bf(const float* __restrict__ x, ushort* __restrict__ xb) {
  const size_t total = (size_t)BDIM * SEQ * DMODEL;
  size_t i = ((size_t)blockIdx.x * 256 + threadIdx.x) * 8;
  if (i >= total) return;
  float4 a = *reinterpret_cast<const float4*>(x + i);
  float4 c = *reinterpret_cast<const float4*>(x + i + 4);
  uint4 o;
  o.x = (uint)f2bf(a.x) | ((uint)f2bf(a.y) << 16);
  o.y = (uint)f2bf(a.z) | ((uint)f2bf(a.w) << 16);
  o.z = (uint)f2bf(c.x) | ((uint)f2bf(c.y) << 16);
  o.w = (uint)f2bf(c.z) | ((uint)f2bf(c.w) << 16);
  *reinterpret_cast<uint4*>(xb + i) = o;
}

// ---------------- zero pad region of transposed V buffer ----------------
__global__ void zero_vpad(ushort* __restrict__ vbuf) {
  int i = blockIdx.x * 256 + threadIdx.x;
  const int total = BDIM * NH * HD * (SP - SEQ);
  if (i >= total) return;
  int s = SEQ + i % (SP - SEQ);
  int row = i / (SP - SEQ);
  vbuf[(size_t)row * SP + s] = 0;
}

// ---------------- rel bias table: rbias[h][qi][ki] ----------------
__global__ void rel_prep(const float* __restrict__ tbl, float* __restrict__ rbias) {
  int i = blockIdx.x * 256 + threadIdx.x;
  if (i >= NH * SEQ * SEQ) return;
  int h = i / (SEQ * SEQ);
  int rem = i - h * SEQ * SEQ;
  int qi = rem / SEQ, ki = rem - qi * SEQ;
  rbias[i] = tbl[relidx(qi, ki) * NH + h];
}

// ---------------- fused QKV GEMM: [148480,768] x [768,2304] ----------------
#define BM 128
#define BN 128
#define BK 64
#define TN_TILES 18

__global__ __launch_bounds__(256)
void qkv_gemm(const ushort* __restrict__ xb, const ushort* __restrict__ Wt,
              const float* __restrict__ bq, const float* __restrict__ bv,
              ushort* __restrict__ qbuf, ushort* __restrict__ kbuf,
              ushort* __restrict__ vbuf) {
  __shared__ __align__(16) ushort Alds[BM * BK];
  __shared__ __align__(16) ushort Blds[BN * BK];

  int id = blockIdx.x;
  // XCD-aware: each XCD walks nt fastest over its own set of m-panels
  int xcd = id & 7;
  int j = id >> 3;
  int mt = xcd + 8 * (j / TN_TILES);
  int nt = j % TN_TILES;
  int m0 = mt * BM, n0 = nt * BN;

  int tid = threadIdx.x;
  int lane = tid & 63, wid = tid >> 6;
  int wr = wid >> 1, wc = wid & 1;

  f32x4 acc[4][4];
  #pragma unroll
  for (int a = 0; a < 4; a++)
    #pragma unroll
    for (int c = 0; c < 4; c++)
      #pragma unroll
      for (int e = 0; e < 4; e++) acc[a][c][e] = 0.f;

  int srow = (wid << 3) + (lane >> 3);   // 0..31 within a 32-row pass
  int scol = (lane & 7) << 3;            // 0..56

  for (int k0 = 0; k0 < DMODEL; k0 += BK) {
    __syncthreads();
    #pragma unroll
    for (int p = 0; p < 4; p++) {
      const ushort* ga = xb + (size_t)(m0 + p * 32 + srow) * DMODEL + k0 + scol;
      const ushort* gb = Wt + (size_t)(n0 + p * 32 + srow) * DMODEL + k0 + scol;
      gload_lds16(ga, (ushort*)((char*)Alds + p * 4096 + wid * 1024));
      gload_lds16(gb, (ushort*)((char*)Blds + p * 4096 + wid * 1024));
    }
    __syncthreads();   // compiler drains vmcnt(0) here

    #pragma unroll
    for (int kk = 0; kk < 2; kk++) {
      int kb = kk * 32 + (lane >> 4) * 8;
      bf16x8 af[4], bfv[4];
      #pragma unroll
      for (int m = 0; m < 4; m++)
        af[m] = *reinterpret_cast<const bf16x8*>(&Alds[(wr * 64 + m * 16 + (lane & 15)) * BK + kb]);
      #pragma unroll
      for (int n = 0; n < 4; n++)
        bfv[n] = *reinterpret_cast<const bf16x8*>(&Blds[(wc * 64 + n * 16 + (lane & 15)) * BK + kb]);
      #pragma unroll
      for (int m = 0; m < 4; m++)
        #pragma unroll
        for (int n = 0; n < 4; n++)
          acc[m][n] = __builtin_amdgcn_mfma_f32_16x16x32_bf16(af[m], bfv[n], acc[m][n], 0, 0, 0);
    }
  }

  // epilogue: which sub-matrix (q/k/v) is uniform per block (768 % 128 == 0)
  int which = n0 / DMODEL;
  #pragma unroll
  for (int nf = 0; nf < 4; nf++) {
    int col = n0 + wc * 64 + nf * 16 + (lane & 15);
    int hcol = col - which * DMODEL;
    int h = hcol >> 6, dh = hcol & 63;
    float bias = (which == 0) ? bq[hcol] : (which == 2 ? bv[hcol] : 0.f);
    #pragma unroll
    for (int mf = 0; mf < 4; mf++) {
      int rowb = m0 + wr * 64 + mf * 16 + ((lane >> 4) << 2);
      #pragma unroll
      for (int r = 0; r < 4; r++) {
        int row = rowb + r;
        int b = row / SEQ;
        int s = row - b * SEQ;
        float v = acc[mf][nf][r] + bias;
        size_t bh = (size_t)b * NH + h;
        if (which == 0) {
          v *= 0.125f;  // fold 1/sqrt(64)
          qbuf[(bh * SEQ + s) * HD + dh] = f2bf(v);
        } else if (which == 1) {
          kbuf[(bh * SEQ + s) * HD + dh] = f2bf(v);
        } else {
          vbuf[(bh * HD + dh) * SP + s] = f2bf(v);  // transposed + padded
        }
      }
    }
  }
}

// ---------------- fused windowed attention (no K/V staging, no barriers) ----------------
__global__ __launch_bounds__(320)
void attn_kernel(const ushort* __restrict__ qbuf, const ushort* __restrict__ kbuf,
                 const ushort* __restrict__ vbuf, const float* __restrict__ mask,
                 const float* __restrict__ rbias, float* __restrict__ out) {
  __shared__ __align__(16) ushort plds[5][16][SP + 8];   // per-wave P transpose, 26.9 KB

  int bh = blockIdx.x;
  int b = bh / NH, h = bh - b * NH;
  int tid = threadIdx.x;
  int lane = tid & 63, wid = tid >> 6;
  int l15 = lane & 15, l4 = lane >> 4;

  const ushort* qp = qbuf + (size_t)bh * SEQ * HD;
  const ushort* kp = kbuf + (size_t)bh * SEQ * HD;
  const ushort* vp = vbuf + (size_t)bh * HD * SP;
  const float* mp = mask + (size_t)b * SEQ * SEQ;
  const float* rp = rbias + (size_t)h * SEQ * SEQ;

  for (int half = 0; half < 2; half++) {
    int r0 = (wid * 2 + half) * 16;
    // Q fragments straight from global (zero OOB rows)
    bf16x8 qf[2];
    int qrow = r0 + l15;
    if (qrow < SEQ) {
      qf[0] = *reinterpret_cast<const bf16x8*>(qp + qrow * HD + l4 * 8);
      qf[1] = *reinterpret_cast<const bf16x8*>(qp + qrow * HD + 32 + l4 * 8);
    } else {
      uint4 z = make_uint4(0, 0, 0, 0);
      qf[0] = *reinterpret_cast<bf16x8*>(&z);
      qf[1] = *reinterpret_cast<bf16x8*>(&z);
    }

    // scores: 10 column tiles, K read direct from global (L2-hot)
    f32x4 sc[10];
    #pragma unroll
    for (int ct = 0; ct < 10; ct++)
      #pragma unroll
      for (int e = 0; e < 4; e++) sc[ct][e] = 0.f;
    #pragma unroll
    for (int ct = 0; ct < 10; ct++) {
      int krow = ct * 16 + l15;
      if (krow >= SEQ) krow = 0;   // clamp: real data, masked below (never NaN)
      #pragma unroll
      for (int kk = 0; kk < 2; kk++) {
        bf16x8 kf = *reinterpret_cast<const bf16x8*>(kp + krow * HD + kk * 32 + l4 * 8);
        sc[ct] = __builtin_amdgcn_mfma_f32_16x16x32_bf16(qf[kk], kf, sc[ct], 0, 0, 0);
      }
    }

    // mask + precomputed rel bias
    int qi[4];
    #pragma unroll
    for (int r = 0; r < 4; r++) qi[r] = r0 + (l4 << 2) + r;
    float mx[4] = {-3e38f, -3e38f, -3e38f, -3e38f};
    #pragma unroll
    for (int ct = 0; ct < 10; ct++) {
      int ki = ct * 16 + l15;
      #pragma unroll
      for (int r = 0; r < 4; r++) {
        float sv;
        if (ki < SEQ && qi[r] < SEQ) {
          int o = qi[r] * SEQ + ki;
          sv = sc[ct][r] + mp[o] + rp[o];
        } else {
          sv = -3e38f;
        }
        sc[ct][r] = sv;
        mx[r] = fmaxf(mx[r], sv);
      }
    }
    // row max across the 16-lane group
    #pragma unroll
    for (int d = 1; d < 16; d <<= 1)
      #pragma unroll
      for (int r = 0; r < 4; r++) mx[r] = fmaxf(mx[r], __shfl_xor(mx[r], d, 64));
    // exp + sum
    float sum[4] = {0.f, 0.f, 0.f, 0.f};
    #pragma unroll
    for (int ct = 0; ct < 10; ct++)
      #pragma unroll
      for (int r = 0; r < 4; r++) {
        float p = __expf(sc[ct][r] - mx[r]);
        sc[ct][r] = p;
        sum[r] += p;
      }
    #pragma unroll
    for (int d = 1; d < 16; d <<= 1)
      #pragma unroll
      for (int r = 0; r < 4; r++) sum[r] += __shfl_xor(sum[r], d, 64);
    float inv[4];
    #pragma unroll
    for (int r = 0; r < 4; r++) inv[r] = 1.f / sum[r];

    // write P (bf16) to per-wave LDS (C-layout -> A-layout transpose)
    #pragma unroll
    for (int ct = 0; ct < 10; ct++) {
      #pragma unroll
      for (int r = 0; r < 4; r++)
        plds[wid][(l4 << 2) + r][ct * 16 + l15] = f2bf(sc[ct][r] * inv[r]);
    }

    // PV: ctx[16 x 64], V^T read direct from global (pad cols are zeroed)
    #pragma unroll
    for (int ntl = 0; ntl < 4; ntl++) {
      f32x4 pacc;
      #pragma unroll
      for (int e = 0; e < 4; e++) pacc[e] = 0.f;
      #pragma unroll
      for (int ks = 0; ks < 5; ks++) {
        bf16x8 pa = *reinterpret_cast<const bf16x8*>(
            &plds[wid][l15][ks * 32 + l4 * 8]);
        bf16x8 vb = *reinterpret_cast<const bf16x8*>(
            vp + (ntl * 16 + l15) * SP + ks * 32 + l4 * 8);
        pacc = __builtin_amdgcn_mfma_f32_16x16x32_bf16(pa, vb, pacc, 0, 0, 0);
      }
      #pragma unroll
      for (int r = 0; r < 4; r++) {
        int s = r0 + (l4 << 2) + r;
        if (s < SEQ)
          out[((size_t)b * SEQ + s) * DMODEL + h * HD + ntl * 16 + l15] = pacc[r];
      }
    }
  }
}

extern "C" void kernel_launch(void* const* d_in, const int* in_sizes, int n_in,
                              void* d_out, int out_size, void* d_ws, size_t ws_size,
                              hipStream_t stream) {
  const float* x    = (const float*)d_in[0];
  const float* mask = (const float*)d_in[1];
  const float* Wq   = (const float*)d_in[2];
  const float* bq   = (const float*)d_in[3];
  const float* Wk   = (const float*)d_in[4];
  const float* Wv   = (const float*)d_in[5];
  const float* bv   = (const float*)d_in[6];
  const float* tbl  = (const float*)d_in[7];
  float* out = (float*)d_out;

  char* ws = (char*)d_ws;
  ushort* Wt = (ushort*)ws;                         // 3,538,944 B
  size_t off = (size_t)NTOT * DMODEL * 2;
  ushort* qbuf = (ushort*)(ws + off); off += (size_t)BDIM * NH * SEQ * HD * 2;
  ushort* kbuf = (ushort*)(ws + off); off += (size_t)BDIM * NH * SEQ * HD * 2;
  ushort* vbuf = (ushort*)(ws + off); off += (size_t)BDIM * NH * HD * SP * 2;
  float*  rbias = (float*)(ws + off); off += (size_t)NH * SEQ * SEQ * 4;
  // ~713 MB of d_ws

  // bf16 x lives in d_out scratch (456 MB f32 out >= 228 MB bf16 x);
  // attn_kernel later overwrites every element of d_out.
  ushort* xbuf = (ushort*)d_out;

  prep_w<<<(NTOT * DMODEL + 255) / 256, 256, 0, stream>>>(Wq, Wk, Wv, Wt);
  zero_vpad<<<(BDIM * NH * HD * (SP - SEQ) + 255) / 256, 256, 0, stream>>>(vbuf);
  rel_prep<<<(NH * SEQ * SEQ + 255) / 256, 256, 0, stream>>>(tbl, rbias);
  {
    size_t total = (size_t)BDIM * SEQ * DMODEL;
    x2bf<<<(int)(total / 8 / 256), 256, 0, stream>>>(x, xbuf);
  }

  int mtiles = (BDIM * SEQ) / BM;   // 1160
  qkv_gemm<<<mtiles * TN_TILES, 256, 0, stream>>>(xbuf, Wt, bq, bv, qbuf, kbuf, vbuf);

  attn_kernel<<<BDIM * NH, 320, 0, stream>>>(qbuf, kbuf, vbuf, mask, rbias, out);
}

// Round 3
// 2248.753 us; speedup vs baseline: 1.5236x; 1.3160x over previous
//
#include <hip/hip_runtime.h>
#include <hip/hip_bf16.h>

typedef __bf16 bf16x8 __attribute__((ext_vector_type(8)));
typedef float f32x4 __attribute__((ext_vector_type(4)));

#define NH 12
#define HD 64
#define SEQ 145
#define SP 160
#define DMODEL 768
#define NTOT 2304
#define BDIM 1024

// f32 -> bf16 RNE
__device__ __forceinline__ ushort f2bf(float f) {
  union { float f; uint u; } a; a.f = f;
  uint u = a.u;
  return (ushort)((u + 0x7FFFu + ((u >> 16) & 1u)) >> 16);
}

__device__ __forceinline__ int relidx(int qi, int ki) {
  if (ki == 0) return (qi == 0) ? 531 : 530;
  if (qi == 0) return 529;
  int q = qi - 1, k = ki - 1;
  int qh = q / 12, qw = q - qh * 12;
  int kh = k / 12, kw = k - kh * 12;
  return (qh - kh + 11) * 23 + (qw - kw + 11);
}

// async global->LDS, 16B per lane; lds dest = wave-uniform base + lane*16
__device__ __forceinline__ void gload_lds16(const ushort* g, ushort* l) {
  __builtin_amdgcn_global_load_lds(
      (const __attribute__((address_space(1))) void*)g,
      (__attribute__((address_space(3))) void*)l, 16, 0, 0);
}

// ---------------- prep: Wt[n][k] = W_sel[k][n%768] as bf16 ----------------
__global__ void prep_w(const float* __restrict__ Wq, const float* __restrict__ Wk,
                       const float* __restrict__ Wv, ushort* __restrict__ Wt) {
  int i = blockIdx.x * 256 + threadIdx.x;
  if (i >= NTOT * DMODEL) return;
  int n = i / DMODEL, k = i - n * DMODEL;
  const float* W = (n < DMODEL) ? Wq : (n < 2 * DMODEL ? Wk : Wv);
  int c = n % DMODEL;
  Wt[i] = f2bf(W[k * DMODEL + c]);
}

// ---------------- x f32 -> bf16 (into d_out scratch) ----------------
__global__ void x2bf(const float* __restrict__ x, ushort* __restrict__ xb) {
  const size_t total = (size_t)BDIM * SEQ * DMODEL;
  size_t i = ((size_t)blockIdx.x * 256 + threadIdx.x) * 8;
  if (i >= total) return;
  float4 a = *reinterpret_cast<const float4*>(x + i);
  float4 c = *reinterpret_cast<const float4*>(x + i + 4);
  uint4 o;
  o.x = (uint)f2bf(a.x) | ((uint)f2bf(a.y) << 16);
  o.y = (uint)f2bf(a.z) | ((uint)f2bf(a.w) << 16);
  o.z = (uint)f2bf(c.x) | ((uint)f2bf(c.y) << 16);
  o.w = (uint)f2bf(c.z) | ((uint)f2bf(c.w) << 16);
  *reinterpret_cast<uint4*>(xb + i) = o;
}

// ---------------- zero pad region of transposed V buffer ----------------
__global__ void zero_vpad(ushort* __restrict__ vbuf) {
  int i = blockIdx.x * 256 + threadIdx.x;
  const int total = BDIM * NH * HD * (SP - SEQ);
  if (i >= total) return;
  int s = SEQ + i % (SP - SEQ);
  int row = i / (SP - SEQ);
  vbuf[(size_t)row * SP + s] = 0;
}

// ---------------- rel bias table: rbias[h][qi][ki] ----------------
__global__ void rel_prep(const float* __restrict__ tbl, float* __restrict__ rbias) {
  int i = blockIdx.x * 256 + threadIdx.x;
  if (i >= NH * SEQ * SEQ) return;
  int h = i / (SEQ * SEQ);
  int rem = i - h * SEQ * SEQ;
  int qi = rem / SEQ, ki = rem - qi * SEQ;
  rbias[i] = tbl[relidx(qi, ki) * NH + h];
}

// ---------------- fused QKV GEMM: [148480,768] x [768,2304] ----------------
#define BM 128
#define BN 128
#define BK 64
#define TN_TILES 18

__global__ __launch_bounds__(256)
void qkv_gemm(const ushort* __restrict__ xb, const ushort* __restrict__ Wt,
              const float* __restrict__ bq, const float* __restrict__ bv,
              ushort* __restrict__ qbuf, ushort* __restrict__ kbuf,
              ushort* __restrict__ vbuf) {
  __shared__ __align__(16) ushort Alds[BM * BK];
  __shared__ __align__(16) ushort Blds[BN * BK];

  int id = blockIdx.x;
  // XCD-aware: each XCD walks nt fastest over its own set of m-panels
  int xcd = id & 7;
  int j = id >> 3;
  int mt = xcd + 8 * (j / TN_TILES);
  int nt = j % TN_TILES;
  int m0 = mt * BM, n0 = nt * BN;

  int tid = threadIdx.x;
  int lane = tid & 63, wid = tid >> 6;
  int wr = wid >> 1, wc = wid & 1;

  f32x4 acc[4][4];
  #pragma unroll
  for (int a = 0; a < 4; a++)
    #pragma unroll
    for (int c = 0; c < 4; c++)
      #pragma unroll
      for (int e = 0; e < 4; e++) acc[a][c][e] = 0.f;

  int srow = (wid << 3) + (lane >> 3);   // 0..31 within a 32-row pass
  int scol = (lane & 7) << 3;            // 0..56

  for (int k0 = 0; k0 < DMODEL; k0 += BK) {
    __syncthreads();
    #pragma unroll
    for (int p = 0; p < 4; p++) {
      const ushort* ga = xb + (size_t)(m0 + p * 32 + srow) * DMODEL + k0 + scol;
      const ushort* gb = Wt + (size_t)(n0 + p * 32 + srow) * DMODEL + k0 + scol;
      gload_lds16(ga, (ushort*)((char*)Alds + p * 4096 + wid * 1024));
      gload_lds16(gb, (ushort*)((char*)Blds + p * 4096 + wid * 1024));
    }
    __syncthreads();   // compiler drains vmcnt(0) here

    #pragma unroll
    for (int kk = 0; kk < 2; kk++) {
      int kb = kk * 32 + (lane >> 4) * 8;
      bf16x8 af[4], bfv[4];
      #pragma unroll
      for (int m = 0; m < 4; m++)
        af[m] = *reinterpret_cast<const bf16x8*>(&Alds[(wr * 64 + m * 16 + (lane & 15)) * BK + kb]);
      #pragma unroll
      for (int n = 0; n < 4; n++)
        bfv[n] = *reinterpret_cast<const bf16x8*>(&Blds[(wc * 64 + n * 16 + (lane & 15)) * BK + kb]);
      #pragma unroll
      for (int m = 0; m < 4; m++)
        #pragma unroll
        for (int n = 0; n < 4; n++)
          acc[m][n] = __builtin_amdgcn_mfma_f32_16x16x32_bf16(af[m], bfv[n], acc[m][n], 0, 0, 0);
    }
  }

  // epilogue: which sub-matrix (q/k/v) is uniform per block (768 % 128 == 0)
  int which = n0 / DMODEL;
  #pragma unroll
  for (int nf = 0; nf < 4; nf++) {
    int col = n0 + wc * 64 + nf * 16 + (lane & 15);
    int hcol = col - which * DMODEL;
    int h = hcol >> 6, dh = hcol & 63;
    float bias = (which == 0) ? bq[hcol] : (which == 2 ? bv[hcol] : 0.f);
    #pragma unroll
    for (int mf = 0; mf < 4; mf++) {
      int rowb = m0 + wr * 64 + mf * 16 + ((lane >> 4) << 2);
      #pragma unroll
      for (int r = 0; r < 4; r++) {
        int row = rowb + r;
        int b = row / SEQ;
        int s = row - b * SEQ;
        float v = acc[mf][nf][r] + bias;
        size_t bh = (size_t)b * NH + h;
        if (which == 0) {
          v *= 0.125f;  // fold 1/sqrt(64)
          qbuf[(bh * SEQ + s) * HD + dh] = f2bf(v);
        } else if (which == 1) {
          kbuf[(bh * SEQ + s) * HD + dh] = f2bf(v);
        } else {
          vbuf[(bh * HD + dh) * SP + s] = f2bf(v);  // transposed + padded
        }
      }
    }
  }
}

// ---------------- fused windowed attention ----------------
// one block = (b, h, half); 5 waves, one 16-row tile each; no barriers.
// XCD b-affinity: all 24 blocks of batch b land on XCD b%8 (mask L2 reuse).
__global__ __launch_bounds__(320, 4)
void attn_kernel(const ushort* __restrict__ qbuf, const ushort* __restrict__ kbuf,
                 const ushort* __restrict__ vbuf, const float* __restrict__ mask,
                 const float* __restrict__ rbias, float* __restrict__ out) {
  __shared__ __align__(16) ushort plds[5][16][SP + 8];   // per-wave P transpose, 26.9 KB

  int i = blockIdx.x;
  int xcd = i & 7;
  int q = i >> 3;                 // 0..3071
  int b = xcd + 8 * (q / 24);     // b % 8 == xcd
  int j = q % 24;
  int h = j >> 1, half = j & 1;
  int bh = b * NH + h;

  int tid = threadIdx.x;
  int lane = tid & 63, wid = tid >> 6;
  int l15 = lane & 15, l4 = lane >> 4;

  const ushort* qp = qbuf + (size_t)bh * SEQ * HD;
  const ushort* kp = kbuf + (size_t)bh * SEQ * HD;
  const ushort* vp = vbuf + (size_t)bh * HD * SP;
  const float* mp = mask + (size_t)b * SEQ * SEQ;
  const float* rp = rbias + (size_t)h * SEQ * SEQ;

  int r0 = (half * 5 + wid) * 16;   // this wave's 16-row tile

  // Q fragments straight from global (zero OOB rows)
  bf16x8 qf[2];
  int qrow = r0 + l15;
  if (qrow < SEQ) {
    qf[0] = *reinterpret_cast<const bf16x8*>(qp + qrow * HD + l4 * 8);
    qf[1] = *reinterpret_cast<const bf16x8*>(qp + qrow * HD + 32 + l4 * 8);
  } else {
    uint4 z = make_uint4(0, 0, 0, 0);
    qf[0] = *reinterpret_cast<bf16x8*>(&z);
    qf[1] = *reinterpret_cast<bf16x8*>(&z);
  }

  int qi[4];
  #pragma unroll
  for (int r = 0; r < 4; r++) qi[r] = r0 + (l4 << 2) + r;

  // mask + rel-bias gathers, issued up-front for MLP; safe-clamped addressing
  float mb[10][4];
  #pragma unroll
  for (int ct = 0; ct < 10; ct++) {
    int ki = ct * 16 + l15;
    int kc = (ki < SEQ) ? ki : (SEQ - 1);
    #pragma unroll
    for (int r = 0; r < 4; r++) {
      int qc = (qi[r] < SEQ) ? qi[r] : (SEQ - 1);
      int o = qc * SEQ + kc;
      float v = mp[o] + rp[o];
      mb[ct][r] = (ki < SEQ && qi[r] < SEQ) ? v : -3e38f;
    }
  }

  // scores: 10 column tiles, K read direct from global
  f32x4 sc[10];
  #pragma unroll
  for (int ct = 0; ct < 10; ct++)
    #pragma unroll
    for (int e = 0; e < 4; e++) sc[ct][e] = 0.f;
  #pragma unroll
  for (int ct = 0; ct < 10; ct++) {
    int krow = ct * 16 + l15;
    if (krow >= SEQ) krow = 0;   // clamp: real data, masked via mb (never NaN)
    #pragma unroll
    for (int kk = 0; kk < 2; kk++) {
      bf16x8 kf = *reinterpret_cast<const bf16x8*>(kp + krow * HD + kk * 32 + l4 * 8);
      sc[ct] = __builtin_amdgcn_mfma_f32_16x16x32_bf16(qf[kk], kf, sc[ct], 0, 0, 0);
    }
  }

  // add mask+bias, row max
  float mx[4] = {-3e38f, -3e38f, -3e38f, -3e38f};
  #pragma unroll
  for (int ct = 0; ct < 10; ct++)
    #pragma unroll
    for (int r = 0; r < 4; r++) {
      float sv = sc[ct][r] + mb[ct][r];
      sc[ct][r] = sv;
      mx[r] = fmaxf(mx[r], sv);
    }
  #pragma unroll
  for (int d = 1; d < 16; d <<= 1)
    #pragma unroll
    for (int r = 0; r < 4; r++) mx[r] = fmaxf(mx[r], __shfl_xor(mx[r], d, 64));

  // exp + sum
  float sum[4] = {0.f, 0.f, 0.f, 0.f};
  #pragma unroll
  for (int ct = 0; ct < 10; ct++)
    #pragma unroll
    for (int r = 0; r < 4; r++) {
      float p = __expf(sc[ct][r] - mx[r]);
      sc[ct][r] = p;
      sum[r] += p;
    }
  #pragma unroll
  for (int d = 1; d < 16; d <<= 1)
    #pragma unroll
    for (int r = 0; r < 4; r++) sum[r] += __shfl_xor(sum[r], d, 64);
  float inv[4];
  #pragma unroll
  for (int r = 0; r < 4; r++) inv[r] = 1.f / sum[r];

  // write P (bf16) to per-wave LDS (C-layout -> A-layout transpose)
  #pragma unroll
  for (int ct = 0; ct < 10; ct++) {
    #pragma unroll
    for (int r = 0; r < 4; r++)
      plds[wid][(l4 << 2) + r][ct * 16 + l15] = f2bf(sc[ct][r] * inv[r]);
  }

  // PV: ctx[16 x 64], V^T read direct from global (pad cols are zeroed)
  #pragma unroll
  for (int ntl = 0; ntl < 4; ntl++) {
    f32x4 pacc;
    #pragma unroll
    for (int e = 0; e < 4; e++) pacc[e] = 0.f;
    #pragma unroll
    for (int ks = 0; ks < 5; ks++) {
      bf16x8 pa = *reinterpret_cast<const bf16x8*>(
          &plds[wid][l15][ks * 32 + l4 * 8]);
      bf16x8 vb = *reinterpret_cast<const bf16x8*>(
          vp + (ntl * 16 + l15) * SP + ks * 32 + l4 * 8);
      pacc = __builtin_amdgcn_mfma_f32_16x16x32_bf16(pa, vb, pacc, 0, 0, 0);
    }
    #pragma unroll
    for (int r = 0; r < 4; r++) {
      int s = r0 + (l4 << 2) + r;
      if (s < SEQ)
        out[((size_t)b * SEQ + s) * DMODEL + h * HD + ntl * 16 + l15] = pacc[r];
    }
  }
}

extern "C" void kernel_launch(void* const* d_in, const int* in_sizes, int n_in,
                              void* d_out, int out_size, void* d_ws, size_t ws_size,
                              hipStream_t stream) {
  const float* x    = (const float*)d_in[0];
  const float* mask = (const float*)d_in[1];
  const float* Wq   = (const float*)d_in[2];
  const float* bq   = (const float*)d_in[3];
  const float* Wk   = (const float*)d_in[4];
  const float* Wv   = (const float*)d_in[5];
  const float* bv   = (const float*)d_in[6];
  const float* tbl  = (const float*)d_in[7];
  float* out = (float*)d_out;

  char* ws = (char*)d_ws;
  ushort* Wt = (ushort*)ws;                         // 3,538,944 B
  size_t off = (size_t)NTOT * DMODEL * 2;
  ushort* qbuf = (ushort*)(ws + off); off += (size_t)BDIM * NH * SEQ * HD * 2;
  ushort* kbuf = (ushort*)(ws + off); off += (size_t)BDIM * NH * SEQ * HD * 2;
  ushort* vbuf = (ushort*)(ws + off); off += (size_t)BDIM * NH * HD * SP * 2;
  float*  rbias = (float*)(ws + off); off += (size_t)NH * SEQ * SEQ * 4;
  // ~713 MB of d_ws

  // bf16 x lives in d_out scratch (456 MB f32 out >= 228 MB bf16 x);
  // attn_kernel later overwrites every element of d_out.
  ushort* xbuf = (ushort*)d_out;

  prep_w<<<(NTOT * DMODEL + 255) / 256, 256, 0, stream>>>(Wq, Wk, Wv, Wt);
  zero_vpad<<<(BDIM * NH * HD * (SP - SEQ) + 255) / 256, 256, 0, stream>>>(vbuf);
  rel_prep<<<(NH * SEQ * SEQ + 255) / 256, 256, 0, stream>>>(tbl, rbias);
  {
    size_t total = (size_t)BDIM * SEQ * DMODEL;
    x2bf<<<(int)(total / 8 / 256), 256, 0, stream>>>(x, xbuf);
  }

  int mtiles = (BDIM * SEQ) / BM;   // 1160
  qkv_gemm<<<mtiles * TN_TILES, 256, 0, stream>>>(xbuf, Wt, bq, bv, qbuf, kbuf, vbuf);

  attn_kernel<<<BDIM * NH * 2, 320, 0, stream>>>(qbuf, kbuf, vbuf, mask, rbias, out);
}

// Round 4
// 1959.136 us; speedup vs baseline: 1.7489x; 1.1478x over previous
//
#include <hip/hip_runtime.h>
#include <hip/hip_bf16.h>

typedef __bf16 bf16x8 __attribute__((ext_vector_type(8)));
typedef float f32x4 __attribute__((ext_vector_type(4)));

#define NH 12
#define HD 64
#define SEQ 145
#define SP 160
#define DMODEL 768
#define NTOT 2304
#define BDIM 1024

// f32 -> bf16 RNE
__device__ __forceinline__ ushort f2bf(float f) {
  union { float f; uint u; } a; a.f = f;
  uint u = a.u;
  return (ushort)((u + 0x7FFFu + ((u >> 16) & 1u)) >> 16);
}

__device__ __forceinline__ int relidx(int qi, int ki) {
  if (ki == 0) return (qi == 0) ? 531 : 530;
  if (qi == 0) return 529;
  int q = qi - 1, k = ki - 1;
  int qh = q / 12, qw = q - qh * 12;
  int kh = k / 12, kw = k - kh * 12;
  return (qh - kh + 11) * 23 + (qw - kw + 11);
}

// async global->LDS, 16B per lane; lds dest = wave-uniform base + lane*16
__device__ __forceinline__ void gload_lds16(const ushort* g, ushort* l) {
  __builtin_amdgcn_global_load_lds(
      (const __attribute__((address_space(1))) void*)g,
      (__attribute__((address_space(3))) void*)l, 16, 0, 0);
}

#define VMCNT(n) do { asm volatile("s_waitcnt vmcnt(" #n ")" ::: "memory"); \
                      __builtin_amdgcn_sched_barrier(0); } while (0)

// ---------------- prep: Wt[n][k] = W_sel[k][n%768] as bf16 ----------------
__global__ void prep_w(const float* __restrict__ Wq, const float* __restrict__ Wk,
                       const float* __restrict__ Wv, ushort* __restrict__ Wt) {
  int i = blockIdx.x * 256 + threadIdx.x;
  if (i >= NTOT * DMODEL) return;
  int n = i / DMODEL, k = i - n * DMODEL;
  const float* W = (n < DMODEL) ? Wq : (n < 2 * DMODEL ? Wk : Wv);
  int c = n % DMODEL;
  Wt[i] = f2bf(W[k * DMODEL + c]);
}

// ---------------- x f32 -> bf16 (into d_out scratch) ----------------
__global__ void x2bf(const float* __restrict__ x, ushort* __restrict__ xb) {
  const size_t total = (size_t)BDIM * SEQ * DMODEL;
  size_t i = ((size_t)blockIdx.x * 256 + threadIdx.x) * 8;
  if (i >= total) return;
  float4 a = *reinterpret_cast<const float4*>(x + i);
  float4 c = *reinterpret_cast<const float4*>(x + i + 4);
  uint4 o;
  o.x = (uint)f2bf(a.x) | ((uint)f2bf(a.y) << 16);
  o.y = (uint)f2bf(a.z) | ((uint)f2bf(a.w) << 16);
  o.z = (uint)f2bf(c.x) | ((uint)f2bf(c.y) << 16);
  o.w = (uint)f2bf(c.z) | ((uint)f2bf(c.w) << 16);
  *reinterpret_cast<uint4*>(xb + i) = o;
}

// ---------------- zero pad region of transposed V buffer ----------------
__global__ void zero_vpad(ushort* __restrict__ vbuf) {
  int i = blockIdx.x * 256 + threadIdx.x;
  const int total = BDIM * NH * HD * (SP - SEQ);
  if (i >= total) return;
  int s = SEQ + i % (SP - SEQ);
  int row = i / (SP - SEQ);
  vbuf[(size_t)row * SP + s] = 0;
}

// ---------------- rel bias table: rbias[h][qi][ki] ----------------
__global__ void rel_prep(const float* __restrict__ tbl, float* __restrict__ rbias) {
  int i = blockIdx.x * 256 + threadIdx.x;
  if (i >= NH * SEQ * SEQ) return;
  int h = i / (SEQ * SEQ);
  int rem = i - h * SEQ * SEQ;
  int qi = rem / SEQ, ki = rem - qi * SEQ;
  rbias[i] = tbl[relidx(qi, ki) * NH + h];
}

// ---------------- fused QKV GEMM: [148480,768] x [768,2304] ----------------
// 256x256 tile, BK=64 as 2 k-chunks of 32; 8 waves (2x4); 128 KB LDS dbuf;
// 4 phases per K-tile, counted vmcnt(4), swizzled LDS (src-side + read-side).
#define GNT 9
#define GNWG 5220   // 580 * 9

// LDS ushort layout:
//  A: ((db*2+kc)<<13) + (row<<5) + slot*8        (rows 0..255, slots 0..3)
//  B: 32768 + same
// swizzle: stored slot s holds data k-slot s ^ ((row>>1)&3)

__global__ __launch_bounds__(512, 2)
void qkv_gemm(const ushort* __restrict__ xb, const ushort* __restrict__ Wt,
              const float* __restrict__ bq, const float* __restrict__ bv,
              ushort* __restrict__ qbuf, ushort* __restrict__ kbuf,
              ushort* __restrict__ vbuf) {
  __shared__ __align__(16) ushort lds[65536];   // 128 KB

  // bijective XCD swizzle (m204): nwg=5220, q=652, r=4
  int bid = blockIdx.x;
  int xcd = bid & 7;
  int j = bid >> 3;
  int logical = (xcd < 4 ? xcd * 653 : 4 * 653 + (xcd - 4) * 652) + j;
  int mt = logical / GNT, nt = logical - (logical / GNT) * GNT;
  int m0 = mt * 256, n0 = nt * 256;

  int tid = threadIdx.x;
  int l = tid & 63, w = tid >> 6;
  int wm = w >> 2, wn = w & 3;
  int l15 = l & 15, l4 = l >> 4;
  int rslot = l4 ^ ((l15 >> 1) & 3);

  // staging source pointers (per-lane, inverse-swizzled)
  int srow = (w << 4) + (l >> 2);
  int sslot = (l & 3) ^ ((l >> 3) & 3);
  const ushort* aSrc0 = xb + (size_t)(m0 + srow) * DMODEL + sslot * 8;
  const ushort* aSrc1 = xb + (size_t)(m0 + 128 + srow) * DMODEL + sslot * 8;
  const ushort* bSrc0 = Wt + (size_t)(n0 + srow) * DMODEL + sslot * 8;
  const ushort* bSrc1 = Wt + (size_t)(n0 + 128 + srow) * DMODEL + sslot * 8;
  int wb16 = (w << 4) << 5;   // (w*16)<<5

#define STAGE_A(db, kc, kof) do { \
    gload_lds16(aSrc0 + (kof), &lds[(((db)*2+(kc))<<13) + wb16]); \
    gload_lds16(aSrc1 + (kof), &lds[(((db)*2+(kc))<<13) + (128<<5) + wb16]); \
  } while (0)
#define STAGE_B(db, kc, kof) do { \
    gload_lds16(bSrc0 + (kof), &lds[32768 + (((db)*2+(kc))<<13) + wb16]); \
    gload_lds16(bSrc1 + (kof), &lds[32768 + (((db)*2+(kc))<<13) + (128<<5) + wb16]); \
  } while (0)

  f32x4 acc[8][4];
  #pragma unroll
  for (int m = 0; m < 8; m++)
    #pragma unroll
    for (int n = 0; n < 4; n++)
      #pragma unroll
      for (int e = 0; e < 4; e++) acc[m][n][e] = 0.f;

  bf16x8 af[8], bfr[2];

#define LOAD_A(db, kk) do { int base_ = ((db)*2+(kk))<<13; \
    _Pragma("unroll") \
    for (int mf_ = 0; mf_ < 8; mf_++) \
      af[mf_] = *reinterpret_cast<const bf16x8*>( \
          &lds[base_ + ((wm*128 + mf_*16 + l15) << 5) + rslot*8]); \
  } while (0)
#define LOAD_B(db, nq, kk) do { int base_ = 32768 + (((db)*2+(kk))<<13); \
    _Pragma("unroll") \
    for (int nf_ = 0; nf_ < 2; nf_++) \
      bfr[nf_] = *reinterpret_cast<const bf16x8*>( \
          &lds[base_ + ((wn*64 + (nq)*32 + nf_*16 + l15) << 5) + rslot*8]); \
  } while (0)
#define MFMA16(nq) do { \
    __builtin_amdgcn_s_setprio(1); \
    _Pragma("unroll") \
    for (int mf_ = 0; mf_ < 8; mf_++) { \
      acc[mf_][(nq)*2+0] = __builtin_amdgcn_mfma_f32_16x16x32_bf16(af[mf_], bfr[0], acc[mf_][(nq)*2+0], 0, 0, 0); \
      acc[mf_][(nq)*2+1] = __builtin_amdgcn_mfma_f32_16x16x32_bf16(af[mf_], bfr[1], acc[mf_][(nq)*2+1], 0, 0, 0); \
    } \
    __builtin_amdgcn_s_setprio(0); \
  } while (0)

  // prologue: stage K-tile 0 fully (8 loads), publish A0/B0
  STAGE_A(0, 0, 0); STAGE_B(0, 0, 0);
  STAGE_A(0, 1, 32); STAGE_B(0, 1, 32);
  VMCNT(4);
  __builtin_amdgcn_s_barrier();

  for (int kt = 0; kt < 12; ++kt) {
    int db = kt & 1, dn = db ^ 1;
    int kof = (kt + 1) * 64;
    // ---- phase 0: nq=0, kk=0 ----
    if (kt < 11) STAGE_A(dn, 0, kof);
    LOAD_A(db, 0); LOAD_B(db, 0, 0);
    __builtin_amdgcn_s_barrier();
    MFMA16(0);
    // ---- phase 1: nq=1, kk=0 ----
    if (kt < 11) STAGE_B(dn, 0, kof);
    LOAD_B(db, 1, 0);
    if (kt < 11) { VMCNT(4); } else { VMCNT(0); }   // retire this tile's k1 chunks
    __builtin_amdgcn_s_barrier();
    MFMA16(1);
    // ---- phase 2: nq=0, kk=1 ----
    if (kt < 11) STAGE_A(dn, 1, kof + 32);
    LOAD_A(db, 1); LOAD_B(db, 0, 1);
    __builtin_amdgcn_s_barrier();
    MFMA16(0);
    // ---- phase 3: nq=1, kk=1 ----
    if (kt < 11) STAGE_B(dn, 1, kof + 32);
    LOAD_B(db, 1, 1);
    if (kt < 11) { VMCNT(4); }                      // retire next tile's k0 chunks
    __builtin_amdgcn_s_barrier();
    MFMA16(1);
  }

  // epilogue: which sub-matrix (q/k/v) is uniform per block (768 % 256 == 0)
  int which = n0 / DMODEL;
  #pragma unroll
  for (int nn = 0; nn < 4; nn++) {
    int col = n0 + wn * 64 + nn * 16 + l15;
    int hcol = col - which * DMODEL;
    int h = hcol >> 6, dh = hcol & 63;
    float bias = (which == 0) ? bq[hcol] : (which == 2 ? bv[hcol] : 0.f);
    #pragma unroll
    for (int mf = 0; mf < 8; mf++) {
      int rowb = m0 + wm * 128 + mf * 16 + (l4 << 2);
      #pragma unroll
      for (int r = 0; r < 4; r++) {
        int row = rowb + r;
        int b = row / SEQ;
        int s = row - b * SEQ;
        float v = acc[mf][nn][r] + bias;
        size_t bh = (size_t)b * NH + h;
        if (which == 0) {
          v *= 0.125f;  // fold 1/sqrt(64)
          qbuf[(bh * SEQ + s) * HD + dh] = f2bf(v);
        } else if (which == 1) {
          kbuf[(bh * SEQ + s) * HD + dh] = f2bf(v);
        } else {
          vbuf[(bh * HD + dh) * SP + s] = f2bf(v);  // transposed + padded
        }
      }
    }
  }
#undef STAGE_A
#undef STAGE_B
#undef LOAD_A
#undef LOAD_B
#undef MFMA16
}

// ---------------- fused windowed attention ----------------
// one block = (b, h, half); 5 waves, one 16-row tile each; no barriers.
// XCD b-affinity: all 24 blocks of batch b land on XCD b%8 (mask L2 reuse).
__global__ __launch_bounds__(320, 4)
void attn_kernel(const ushort* __restrict__ qbuf, const ushort* __restrict__ kbuf,
                 const ushort* __restrict__ vbuf, const float* __restrict__ mask,
                 const float* __restrict__ rbias, float* __restrict__ out) {
  __shared__ __align__(16) ushort plds[5][16][SP + 8];   // per-wave P transpose, 26.9 KB

  int i = blockIdx.x;
  int xcd = i & 7;
  int q = i >> 3;                 // 0..3071
  int b = xcd + 8 * (q / 24);     // b % 8 == xcd
  int j = q % 24;
  int h = j >> 1, half = j & 1;
  int bh = b * NH + h;

  int tid = threadIdx.x;
  int lane = tid & 63, wid = tid >> 6;
  int l15 = lane & 15, l4 = lane >> 4;

  const ushort* qp = qbuf + (size_t)bh * SEQ * HD;
  const ushort* kp = kbuf + (size_t)bh * SEQ * HD;
  const ushort* vp = vbuf + (size_t)bh * HD * SP;
  const float* mp = mask + (size_t)b * SEQ * SEQ;
  const float* rp = rbias + (size_t)h * SEQ * SEQ;

  int r0 = (half * 5 + wid) * 16;   // this wave's 16-row tile

  // Q fragments straight from global (zero OOB rows)
  bf16x8 qf[2];
  int qrow = r0 + l15;
  if (qrow < SEQ) {
    qf[0] = *reinterpret_cast<const bf16x8*>(qp + qrow * HD + l4 * 8);
    qf[1] = *reinterpret_cast<const bf16x8*>(qp + qrow * HD + 32 + l4 * 8);
  } else {
    uint4 z = make_uint4(0, 0, 0, 0);
    qf[0] = *reinterpret_cast<bf16x8*>(&z);
    qf[1] = *reinterpret_cast<bf16x8*>(&z);
  }

  int qi[4];
  #pragma unroll
  for (int r = 0; r < 4; r++) qi[r] = r0 + (l4 << 2) + r;

  // mask + rel-bias gathers, issued up-front for MLP; safe-clamped addressing
  float mb[10][4];
  #pragma unroll
  for (int ct = 0; ct < 10; ct++) {
    int ki = ct * 16 + l15;
    int kc = (ki < SEQ) ? ki : (SEQ - 1);
    #pragma unroll
    for (int r = 0; r < 4; r++) {
      int qc = (qi[r] < SEQ) ? qi[r] : (SEQ - 1);
      int o = qc * SEQ + kc;
      float v = mp[o] + rp[o];
      mb[ct][r] = (ki < SEQ && qi[r] < SEQ) ? v : -3e38f;
    }
  }

  // scores: 10 column tiles, K read direct from global
  f32x4 sc[10];
  #pragma unroll
  for (int ct = 0; ct < 10; ct++)
    #pragma unroll
    for (int e = 0; e < 4; e++) sc[ct][e] = 0.f;
  #pragma unroll
  for (int ct = 0; ct < 10; ct++) {
    int krow = ct * 16 + l15;
    if (krow >= SEQ) krow = 0;   // clamp: real data, masked via mb (never NaN)
    #pragma unroll
    for (int kk = 0; kk < 2; kk++) {
      bf16x8 kf = *reinterpret_cast<const bf16x8*>(kp + krow * HD + kk * 32 + l4 * 8);
      sc[ct] = __builtin_amdgcn_mfma_f32_16x16x32_bf16(qf[kk], kf, sc[ct], 0, 0, 0);
    }
  }

  // add mask+bias, row max
  float mx[4] = {-3e38f, -3e38f, -3e38f, -3e38f};
  #pragma unroll
  for (int ct = 0; ct < 10; ct++)
    #pragma unroll
    for (int r = 0; r < 4; r++) {
      float sv = sc[ct][r] + mb[ct][r];
      sc[ct][r] = sv;
      mx[r] = fmaxf(mx[r], sv);
    }
  #pragma unroll
  for (int d = 1; d < 16; d <<= 1)
    #pragma unroll
    for (int r = 0; r < 4; r++) mx[r] = fmaxf(mx[r], __shfl_xor(mx[r], d, 64));

  // exp + sum
  float sum[4] = {0.f, 0.f, 0.f, 0.f};
  #pragma unroll
  for (int ct = 0; ct < 10; ct++)
    #pragma unroll
    for (int r = 0; r < 4; r++) {
      float p = __expf(sc[ct][r] - mx[r]);
      sc[ct][r] = p;
      sum[r] += p;
    }
  #pragma unroll
  for (int d = 1; d < 16; d <<= 1)
    #pragma unroll
    for (int r = 0; r < 4; r++) sum[r] += __shfl_xor(sum[r], d, 64);
  float inv[4];
  #pragma unroll
  for (int r = 0; r < 4; r++) inv[r] = 1.f / sum[r];

  // write P (bf16) to per-wave LDS (C-layout -> A-layout transpose)
  #pragma unroll
  for (int ct = 0; ct < 10; ct++) {
    #pragma unroll
    for (int r = 0; r < 4; r++)
      plds[wid][(l4 << 2) + r][ct * 16 + l15] = f2bf(sc[ct][r] * inv[r]);
  }

  // PV: ctx[16 x 64], V^T read direct from global (pad cols are zeroed)
  #pragma unroll
  for (int ntl = 0; ntl < 4; ntl++) {
    f32x4 pacc;
    #pragma unroll
    for (int e = 0; e < 4; e++) pacc[e] = 0.f;
    #pragma unroll
    for (int ks = 0; ks < 5; ks++) {
      bf16x8 pa = *reinterpret_cast<const bf16x8*>(
          &plds[wid][l15][ks * 32 + l4 * 8]);
      bf16x8 vb = *reinterpret_cast<const bf16x8*>(
          vp + (ntl * 16 + l15) * SP + ks * 32 + l4 * 8);
      pacc = __builtin_amdgcn_mfma_f32_16x16x32_bf16(pa, vb, pacc, 0, 0, 0);
    }
    #pragma unroll
    for (int r = 0; r < 4; r++) {
      int s = r0 + (l4 << 2) + r;
      if (s < SEQ)
        out[((size_t)b * SEQ + s) * DMODEL + h * HD + ntl * 16 + l15] = pacc[r];
    }
  }
}

extern "C" void kernel_launch(void* const* d_in, const int* in_sizes, int n_in,
                              void* d_out, int out_size, void* d_ws, size_t ws_size,
                              hipStream_t stream) {
  const float* x    = (const float*)d_in[0];
  const float* mask = (const float*)d_in[1];
  const float* Wq   = (const float*)d_in[2];
  const float* bq   = (const float*)d_in[3];
  const float* Wk   = (const float*)d_in[4];
  const float* Wv   = (const float*)d_in[5];
  const float* bv   = (const float*)d_in[6];
  const float* tbl  = (const float*)d_in[7];
  float* out = (float*)d_out;

  char* ws = (char*)d_ws;
  ushort* Wt = (ushort*)ws;                         // 3,538,944 B
  size_t off = (size_t)NTOT * DMODEL * 2;
  ushort* qbuf = (ushort*)(ws + off); off += (size_t)BDIM * NH * SEQ * HD * 2;
  ushort* kbuf = (ushort*)(ws + off); off += (size_t)BDIM * NH * SEQ * HD * 2;
  ushort* vbuf = (ushort*)(ws + off); off += (size_t)BDIM * NH * HD * SP * 2;
  float*  rbias = (float*)(ws + off); off += (size_t)NH * SEQ * SEQ * 4;
  // ~713 MB of d_ws

  // bf16 x lives in d_out scratch (456 MB f32 out >= 228 MB bf16 x);
  // attn_kernel later overwrites every element of d_out.
  ushort* xbuf = (ushort*)d_out;

  prep_w<<<(NTOT * DMODEL + 255) / 256, 256, 0, stream>>>(Wq, Wk, Wv, Wt);
  zero_vpad<<<(BDIM * NH * HD * (SP - SEQ) + 255) / 256, 256, 0, stream>>>(vbuf);
  rel_prep<<<(NH * SEQ * SEQ + 255) / 256, 256, 0, stream>>>(tbl, rbias);
  {
    size_t total = (size_t)BDIM * SEQ * DMODEL;
    x2bf<<<(int)(total / 8 / 256), 256, 0, stream>>>(x, xbuf);
  }

  qkv_gemm<<<GNWG, 512, 0, stream>>>(xbuf, Wt, bq, bv, qbuf, kbuf, vbuf);

  attn_kernel<<<BDIM * NH * 2, 320, 0, stream>>>(qbuf, kbuf, vbuf, mask, rbias, out);
}

// Round 5
// 1766.970 us; speedup vs baseline: 1.9391x; 1.1088x over previous
//
#include <hip/hip_runtime.h>
#include <hip/hip_bf16.h>

typedef __bf16 bf16x8 __attribute__((ext_vector_type(8)));
typedef float f32x4 __attribute__((ext_vector_type(4)));

#define NH 12
#define HD 64
#define SEQ 145
#define SP 160
#define DMODEL 768
#define NTOT 2304
#define BDIM 1024

// f32 -> bf16 RNE
__device__ __forceinline__ ushort f2bf(float f) {
  union { float f; uint u; } a; a.f = f;
  uint u = a.u;
  return (ushort)((u + 0x7FFFu + ((u >> 16) & 1u)) >> 16);
}

__device__ __forceinline__ int relidx(int qi, int ki) {
  if (ki == 0) return (qi == 0) ? 531 : 530;
  if (qi == 0) return 529;
  int q = qi - 1, k = ki - 1;
  int qh = q / 12, qw = q - qh * 12;
  int kh = k / 12, kw = k - kh * 12;
  return (qh - kh + 11) * 23 + (qw - kw + 11);
}

// async global->LDS, 16B per lane; lds dest = wave-uniform base + lane*16
__device__ __forceinline__ void gload_lds16(const ushort* g, ushort* l) {
  __builtin_amdgcn_global_load_lds(
      (const __attribute__((address_space(1))) void*)g,
      (__attribute__((address_space(3))) void*)l, 16, 0, 0);
}

#define VMCNT(n) do { asm volatile("s_waitcnt vmcnt(" #n ")" ::: "memory"); \
                      __builtin_amdgcn_sched_barrier(0); } while (0)

// ---------------- prep: Wt[n][k] = W_sel[k][n%768] as bf16 ----------------
__global__ void prep_w(const float* __restrict__ Wq, const float* __restrict__ Wk,
                       const float* __restrict__ Wv, ushort* __restrict__ Wt) {
  int i = blockIdx.x * 256 + threadIdx.x;
  if (i >= NTOT * DMODEL) return;
  int n = i / DMODEL, k = i - n * DMODEL;
  const float* W = (n < DMODEL) ? Wq : (n < 2 * DMODEL ? Wk : Wv);
  int c = n % DMODEL;
  Wt[i] = f2bf(W[k * DMODEL + c]);
}

// ---------------- x f32 -> bf16 (into d_out scratch) ----------------
__global__ void x2bf(const float* __restrict__ x, ushort* __restrict__ xb) {
  const size_t total = (size_t)BDIM * SEQ * DMODEL;
  size_t i = ((size_t)blockIdx.x * 256 + threadIdx.x) * 8;
  if (i >= total) return;
  float4 a = *reinterpret_cast<const float4*>(x + i);
  float4 c = *reinterpret_cast<const float4*>(x + i + 4);
  uint4 o;
  o.x = (uint)f2bf(a.x) | ((uint)f2bf(a.y) << 16);
  o.y = (uint)f2bf(a.z) | ((uint)f2bf(a.w) << 16);
  o.z = (uint)f2bf(c.x) | ((uint)f2bf(c.y) << 16);
  o.w = (uint)f2bf(c.z) | ((uint)f2bf(c.w) << 16);
  *reinterpret_cast<uint4*>(xb + i) = o;
}

// ---------------- zero pad region of transposed V buffer ----------------
__global__ void zero_vpad(ushort* __restrict__ vbuf) {
  int i = blockIdx.x * 256 + threadIdx.x;
  const int total = BDIM * NH * HD * (SP - SEQ);
  if (i >= total) return;
  int s = SEQ + i % (SP - SEQ);
  int row = i / (SP - SEQ);
  vbuf[(size_t)row * SP + s] = 0;
}

// ---------------- rel bias table: rbias[h][qi][ki] ----------------
__global__ void rel_prep(const float* __restrict__ tbl, float* __restrict__ rbias) {
  int i = blockIdx.x * 256 + threadIdx.x;
  if (i >= NH * SEQ * SEQ) return;
  int h = i / (SEQ * SEQ);
  int rem = i - h * SEQ * SEQ;
  int qi = rem / SEQ, ki = rem - qi * SEQ;
  rbias[i] = tbl[relidx(qi, ki) * NH + h];
}

// ---------------- fused QKV GEMM: [148480,768] x [768,2304] ----------------
// 256x256 tile, BK=64 as 2 k-chunks of 32; 8 waves (2x4); 128 KB LDS dbuf;
// 4 phases per K-tile, counted vmcnt(4), swizzled LDS (src-side + read-side).
#define GNT 9
#define GNWG 5220   // 580 * 9

__global__ __launch_bounds__(512, 2)
void qkv_gemm(const ushort* __restrict__ xb, const ushort* __restrict__ Wt,
              const float* __restrict__ bq, const float* __restrict__ bv,
              ushort* __restrict__ qbuf, ushort* __restrict__ kbuf,
              ushort* __restrict__ vbuf) {
  __shared__ __align__(16) ushort lds[65536];   // 128 KB

  // bijective XCD swizzle (m204): nwg=5220, q=652, r=4
  int bid = blockIdx.x;
  int xcd = bid & 7;
  int j = bid >> 3;
  int logical = (xcd < 4 ? xcd * 653 : 4 * 653 + (xcd - 4) * 652) + j;
  int mt = logical / GNT, nt = logical - (logical / GNT) * GNT;
  int m0 = mt * 256, n0 = nt * 256;

  int tid = threadIdx.x;
  int l = tid & 63, w = tid >> 6;
  int wm = w >> 2, wn = w & 3;
  int l15 = l & 15, l4 = l >> 4;
  int rslot = l4 ^ ((l15 >> 1) & 3);

  // staging source pointers (per-lane, inverse-swizzled)
  int srow = (w << 4) + (l >> 2);
  int sslot = (l & 3) ^ ((l >> 3) & 3);
  const ushort* aSrc0 = xb + (size_t)(m0 + srow) * DMODEL + sslot * 8;
  const ushort* aSrc1 = xb + (size_t)(m0 + 128 + srow) * DMODEL + sslot * 8;
  const ushort* bSrc0 = Wt + (size_t)(n0 + srow) * DMODEL + sslot * 8;
  const ushort* bSrc1 = Wt + (size_t)(n0 + 128 + srow) * DMODEL + sslot * 8;
  int wb16 = (w << 4) << 5;   // (w*16)<<5

#define STAGE_A(db, kc, kof) do { \
    gload_lds16(aSrc0 + (kof), &lds[(((db)*2+(kc))<<13) + wb16]); \
    gload_lds16(aSrc1 + (kof), &lds[(((db)*2+(kc))<<13) + (128<<5) + wb16]); \
  } while (0)
#define STAGE_B(db, kc, kof) do { \
    gload_lds16(bSrc0 + (kof), &lds[32768 + (((db)*2+(kc))<<13) + wb16]); \
    gload_lds16(bSrc1 + (kof), &lds[32768 + (((db)*2+(kc))<<13) + (128<<5) + wb16]); \
  } while (0)

  f32x4 acc[8][4];
  #pragma unroll
  for (int m = 0; m < 8; m++)
    #pragma unroll
    for (int n = 0; n < 4; n++)
      #pragma unroll
      for (int e = 0; e < 4; e++) acc[m][n][e] = 0.f;

  bf16x8 af[8], bfr[2];

#define LOAD_A(db, kk) do { int base_ = ((db)*2+(kk))<<13; \
    _Pragma("unroll") \
    for (int mf_ = 0; mf_ < 8; mf_++) \
      af[mf_] = *reinterpret_cast<const bf16x8*>( \
          &lds[base_ + ((wm*128 + mf_*16 + l15) << 5) + rslot*8]); \
  } while (0)
#define LOAD_B(db, nq, kk) do { int base_ = 32768 + (((db)*2+(kk))<<13); \
    _Pragma("unroll") \
    for (int nf_ = 0; nf_ < 2; nf_++) \
      bfr[nf_] = *reinterpret_cast<const bf16x8*>( \
          &lds[base_ + ((wn*64 + (nq)*32 + nf_*16 + l15) << 5) + rslot*8]); \
  } while (0)
#define MFMA16(nq) do { \
    __builtin_amdgcn_s_setprio(1); \
    _Pragma("unroll") \
    for (int mf_ = 0; mf_ < 8; mf_++) { \
      acc[mf_][(nq)*2+0] = __builtin_amdgcn_mfma_f32_16x16x32_bf16(af[mf_], bfr[0], acc[mf_][(nq)*2+0], 0, 0, 0); \
      acc[mf_][(nq)*2+1] = __builtin_amdgcn_mfma_f32_16x16x32_bf16(af[mf_], bfr[1], acc[mf_][(nq)*2+1], 0, 0, 0); \
    } \
    __builtin_amdgcn_s_setprio(0); \
  } while (0)

  // prologue: stage K-tile 0 fully (8 loads), publish A0/B0
  STAGE_A(0, 0, 0); STAGE_B(0, 0, 0);
  STAGE_A(0, 1, 32); STAGE_B(0, 1, 32);
  VMCNT(4);
  __builtin_amdgcn_s_barrier();

  for (int kt = 0; kt < 12; ++kt) {
    int db = kt & 1, dn = db ^ 1;
    int kof = (kt + 1) * 64;
    // ---- phase 0: nq=0, kk=0 ----
    if (kt < 11) STAGE_A(dn, 0, kof);
    LOAD_A(db, 0); LOAD_B(db, 0, 0);
    __builtin_amdgcn_s_barrier();
    MFMA16(0);
    // ---- phase 1: nq=1, kk=0 ----
    if (kt < 11) STAGE_B(dn, 0, kof);
    LOAD_B(db, 1, 0);
    if (kt < 11) { VMCNT(4); } else { VMCNT(0); }   // retire this tile's k1 chunks
    __builtin_amdgcn_s_barrier();
    MFMA16(1);
    // ---- phase 2: nq=0, kk=1 ----
    if (kt < 11) STAGE_A(dn, 1, kof + 32);
    LOAD_A(db, 1); LOAD_B(db, 0, 1);
    __builtin_amdgcn_s_barrier();
    MFMA16(0);
    // ---- phase 3: nq=1, kk=1 ----
    if (kt < 11) STAGE_B(dn, 1, kof + 32);
    LOAD_B(db, 1, 1);
    if (kt < 11) { VMCNT(4); }                      // retire next tile's k0 chunks
    __builtin_amdgcn_s_barrier();
    MFMA16(1);
  }

  // epilogue: which sub-matrix (q/k/v) is uniform per block (768 % 256 == 0)
  int which = n0 / DMODEL;
  #pragma unroll
  for (int nn = 0; nn < 4; nn++) {
    int col = n0 + wn * 64 + nn * 16 + l15;
    int hcol = col - which * DMODEL;
    int h = hcol >> 6, dh = hcol & 63;
    float bias = (which == 0) ? bq[hcol] : (which == 2 ? bv[hcol] : 0.f);
    #pragma unroll
    for (int mf = 0; mf < 8; mf++) {
      int rowb = m0 + wm * 128 + mf * 16 + (l4 << 2);
      #pragma unroll
      for (int r = 0; r < 4; r++) {
        int row = rowb + r;
        int b = row / SEQ;
        int s = row - b * SEQ;
        float v = acc[mf][nn][r] + bias;
        size_t bh = (size_t)b * NH + h;
        if (which == 0) {
          v *= 0.125f;  // fold 1/sqrt(64)
          qbuf[(bh * SEQ + s) * HD + dh] = f2bf(v);
        } else if (which == 1) {
          kbuf[(bh * SEQ + s) * HD + dh] = f2bf(v);
        } else {
          vbuf[(bh * HD + dh) * SP + s] = f2bf(v);  // transposed + padded
        }
      }
    }
  }
#undef STAGE_A
#undef STAGE_B
#undef LOAD_A
#undef LOAD_B
#undef MFMA16
}

// ---------------- fused windowed attention ----------------
// one block = (b, 16-row strip); 12 waves = 12 heads. Mask strip staged once
// in LDS and shared by all heads. XCD b-affinity: b % 8 == xcd (K/V/mask L2 reuse).
__global__ __launch_bounds__(768, 6)
void attn_kernel(const ushort* __restrict__ qbuf, const ushort* __restrict__ kbuf,
                 const ushort* __restrict__ vbuf, const float* __restrict__ mask,
                 const float* __restrict__ rbias, float* __restrict__ out) {
  __shared__ float mlds[16][160];                        // 10.2 KB mask strip
  __shared__ __align__(16) ushort plds[NH][16][SP + 8];  // per-wave P, 64.5 KB

  int i = blockIdx.x;
  int xcd = i & 7;
  int j = i >> 3;                 // 0..1279
  int b = xcd + 8 * (j / 10);     // b % 8 == xcd
  int strip = j % 10;
  int r0 = strip * 16;

  int tid = threadIdx.x;
  int lane = tid & 63, h = tid >> 6;   // wave id == head
  int l15 = lane & 15, l4 = lane >> 4;
  int bh = b * NH + h;

  const ushort* qp = qbuf + (size_t)bh * SEQ * HD;
  const ushort* kp = kbuf + (size_t)bh * SEQ * HD;
  const ushort* vp = vbuf + (size_t)bh * HD * SP;
  const float* mp = mask + (size_t)b * SEQ * SEQ;
  const float* rp = rbias + (size_t)h * SEQ * SEQ;

  // stage mask strip [16][145] into LDS (row-clamped; OOB cols read masked)
  for (int idx = tid; idx < 16 * SEQ; idx += 768) {
    int row = idx / SEQ, col = idx - row * SEQ;
    int gr = r0 + row; if (gr >= SEQ) gr = SEQ - 1;
    mlds[row][col] = mp[gr * SEQ + col];
  }
  __syncthreads();

  // Q fragments straight from global (zero OOB rows)
  bf16x8 qf[2];
  int qrow = r0 + l15;
  if (qrow < SEQ) {
    qf[0] = *reinterpret_cast<const bf16x8*>(qp + qrow * HD + l4 * 8);
    qf[1] = *reinterpret_cast<const bf16x8*>(qp + qrow * HD + 32 + l4 * 8);
  } else {
    uint4 z = make_uint4(0, 0, 0, 0);
    qf[0] = *reinterpret_cast<bf16x8*>(&z);
    qf[1] = *reinterpret_cast<bf16x8*>(&z);
  }

  int qi[4];
  #pragma unroll
  for (int r = 0; r < 4; r++) qi[r] = r0 + (l4 << 2) + r;

  // scores: 10 column tiles, K read direct from global (L2-hot across strips)
  f32x4 sc[10];
  #pragma unroll
  for (int ct = 0; ct < 10; ct++)
    #pragma unroll
    for (int e = 0; e < 4; e++) sc[ct][e] = 0.f;
  #pragma unroll
  for (int ct = 0; ct < 10; ct++) {
    int krow = ct * 16 + l15;
    if (krow >= SEQ) krow = 0;   // clamp: real data, masked below (never NaN)
    #pragma unroll
    for (int kk = 0; kk < 2; kk++) {
      bf16x8 kf = *reinterpret_cast<const bf16x8*>(kp + krow * HD + kk * 32 + l4 * 8);
      sc[ct] = __builtin_amdgcn_mfma_f32_16x16x32_bf16(qf[kk], kf, sc[ct], 0, 0, 0);
    }
  }

  // add mask (LDS) + rel bias (L2 gather), row max
  float mx[4] = {-3e38f, -3e38f, -3e38f, -3e38f};
  #pragma unroll
  for (int ct = 0; ct < 10; ct++) {
    int ki = ct * 16 + l15;
    int kc = (ki < SEQ) ? ki : (SEQ - 1);
    #pragma unroll
    for (int r = 0; r < 4; r++) {
      int lrow = (l4 << 2) + r;
      int qc = (qi[r] < SEQ) ? qi[r] : (SEQ - 1);
      float rb = rp[qc * SEQ + kc];
      float m = mlds[lrow][ki];          // ki<160 in bounds; garbage masked below
      float sv = (ki < SEQ && qi[r] < SEQ) ? (sc[ct][r] + m + rb) : -3e38f;
      sc[ct][r] = sv;
      mx[r] = fmaxf(mx[r], sv);
    }
  }
  #pragma unroll
  for (int d = 1; d < 16; d <<= 1)
    #pragma unroll
    for (int r = 0; r < 4; r++) mx[r] = fmaxf(mx[r], __shfl_xor(mx[r], d, 64));

  // exp + sum
  float sum[4] = {0.f, 0.f, 0.f, 0.f};
  #pragma unroll
  for (int ct = 0; ct < 10; ct++)
    #pragma unroll
    for (int r = 0; r < 4; r++) {
      float p = __expf(sc[ct][r] - mx[r]);
      sc[ct][r] = p;
      sum[r] += p;
    }
  #pragma unroll
  for (int d = 1; d < 16; d <<= 1)
    #pragma unroll
    for (int r = 0; r < 4; r++) sum[r] += __shfl_xor(sum[r], d, 64);
  float inv[4];
  #pragma unroll
  for (int r = 0; r < 4; r++) inv[r] = 1.f / sum[r];

  // write P (bf16) to per-wave LDS (C-layout -> A-layout transpose)
  #pragma unroll
  for (int ct = 0; ct < 10; ct++) {
    #pragma unroll
    for (int r = 0; r < 4; r++)
      plds[h][(l4 << 2) + r][ct * 16 + l15] = f2bf(sc[ct][r] * inv[r]);
  }

  // PV: ctx[16 x 64], V^T read direct from global (pad cols are zeroed)
  #pragma unroll
  for (int ntl = 0; ntl < 4; ntl++) {
    f32x4 pacc;
    #pragma unroll
    for (int e = 0; e < 4; e++) pacc[e] = 0.f;
    #pragma unroll
    for (int ks = 0; ks < 5; ks++) {
      bf16x8 pa = *reinterpret_cast<const bf16x8*>(
          &plds[h][l15][ks * 32 + l4 * 8]);
      bf16x8 vb = *reinterpret_cast<const bf16x8*>(
          vp + (ntl * 16 + l15) * SP + ks * 32 + l4 * 8);
      pacc = __builtin_amdgcn_mfma_f32_16x16x32_bf16(pa, vb, pacc, 0, 0, 0);
    }
    #pragma unroll
    for (int r = 0; r < 4; r++) {
      int s = r0 + (l4 << 2) + r;
      if (s < SEQ)
        out[((size_t)b * SEQ + s) * DMODEL + h * HD + ntl * 16 + l15] = pacc[r];
    }
  }
}

extern "C" void kernel_launch(void* const* d_in, const int* in_sizes, int n_in,
                              void* d_out, int out_size, void* d_ws, size_t ws_size,
                              hipStream_t stream) {
  const float* x    = (const float*)d_in[0];
  const float* mask = (const float*)d_in[1];
  const float* Wq   = (const float*)d_in[2];
  const float* bq   = (const float*)d_in[3];
  const float* Wk   = (const float*)d_in[4];
  const float* Wv   = (const float*)d_in[5];
  const float* bv   = (const float*)d_in[6];
  const float* tbl  = (const float*)d_in[7];
  float* out = (float*)d_out;

  char* ws = (char*)d_ws;
  ushort* Wt = (ushort*)ws;                         // 3,538,944 B
  size_t off = (size_t)NTOT * DMODEL * 2;
  ushort* qbuf = (ushort*)(ws + off); off += (size_t)BDIM * NH * SEQ * HD * 2;
  ushort* kbuf = (ushort*)(ws + off); off += (size_t)BDIM * NH * SEQ * HD * 2;
  ushort* vbuf = (ushort*)(ws + off); off += (size_t)BDIM * NH * HD * SP * 2;
  float*  rbias = (float*)(ws + off); off += (size_t)NH * SEQ * SEQ * 4;
  // ~713 MB of d_ws

  // bf16 x lives in d_out scratch (456 MB f32 out >= 228 MB bf16 x);
  // attn_kernel later overwrites every element of d_out.
  ushort* xbuf = (ushort*)d_out;

  prep_w<<<(NTOT * DMODEL + 255) / 256, 256, 0, stream>>>(Wq, Wk, Wv, Wt);
  zero_vpad<<<(BDIM * NH * HD * (SP - SEQ) + 255) / 256, 256, 0, stream>>>(vbuf);
  rel_prep<<<(NH * SEQ * SEQ + 255) / 256, 256, 0, stream>>>(tbl, rbias);
  {
    size_t total = (size_t)BDIM * SEQ * DMODEL;
    x2bf<<<(int)(total / 8 / 256), 256, 0, stream>>>(x, xbuf);
  }

  qkv_gemm<<<GNWG, 512, 0, stream>>>(xbuf, Wt, bq, bv, qbuf, kbuf, vbuf);

  attn_kernel<<<BDIM * 10, 768, 0, stream>>>(qbuf, kbuf, vbuf, mask, rbias, out);
}